// Round 1
// baseline (398.132 us; speedup 1.0000x reference)
//
#include <hip/hip_runtime.h>

#define NPIX   768
#define PP     256
#define NTERMS 128
#define EPSF   1e-15f

// ---------------------------------------------------------------------------
// Kernel 1: W[i][j] = sum_n basis[n][i][j] * coeffs[n]
// One thread per float4 of W (768*192 threads). basis read fully coalesced
// 16B/lane. coeffs staged in LDS. Memory-bound: 302 MB streamed once.
// ---------------------------------------------------------------------------
__global__ __launch_bounds__(256) void latent_kernel(
    const float* __restrict__ basis,
    const float* __restrict__ coeffs,
    float* __restrict__ W)
{
    __shared__ float sc[NTERMS];
    if (threadIdx.x < NTERMS) sc[threadIdx.x] = coeffs[threadIdx.x];
    __syncthreads();

    const int t = blockIdx.x * 256 + threadIdx.x;      // 0 .. 147455
    const float4* __restrict__ b4 = (const float4*)basis;
    const int stride = NPIX * (NPIX / 4);              // 147456 float4 per term
    const float4* __restrict__ p = b4 + t;

    float4 acc = make_float4(0.f, 0.f, 0.f, 0.f);
    #pragma unroll 8
    for (int n = 0; n < NTERMS; ++n) {
        float4 v = p[(long)n * stride];
        float cn = sc[n];
        acc.x = fmaf(v.x, cn, acc.x);
        acc.y = fmaf(v.y, cn, acc.y);
        acc.z = fmaf(v.z, cn, acc.z);
        acc.w = fmaf(v.w, cn, acc.w);
    }
    ((float4*)W)[t] = acc;
}

// ---------------------------------------------------------------------------
// Closed-form CLIMB area for one 3x3 patch.
// f[m], m = q*3+s  corresponds to sample at x = s/2, y = q/2.
// Least-squares plane fit (regressors orthogonal after centering):
//   a = (sum_{s=2} - sum_{s=0}) / 3
//   b = (sum_{q=2} - sum_{q=0}) / 3
//   c = mean - 0.5*(a+b)
// ---------------------------------------------------------------------------
__device__ __forceinline__ float climb_area(const float f[9])
{
    float sum = 0.f;
    #pragma unroll
    for (int m = 0; m < 9; ++m) sum += f[m];
    float mean = sum * (1.f / 9.f);

    float a = (f[2] + f[5] + f[8] - f[0] - f[3] - f[6]) * (1.f / 3.f);
    float b = (f[6] + f[7] + f[8] - f[0] - f[1] - f[2]) * (1.f / 3.f);
    float c = mean - 0.5f * (a + b);

    if (a == 0.f) a = EPSF;
    if (b == 0.f) b = EPSF;
    if (c == 0.f) c = EPSF;

    float x1 = (-b - c) / a;
    float x2 = -c / a;
    float lo = fminf(x1, x2);
    float hi = fmaxf(x1, x2);
    x1 = fmaxf(lo, 0.f);
    x2 = fminf(hi, 1.f);

    float cb = -c / b;
    float ab = 0.5f * (a / b);
    float d = x1 + cb * x2 - ab * x2 * x2 - cb * x1 + ab * x1 * x1;

    d = (d >= 0.5f) ? d : 1.f - d;
    d = (mean >= 0.f) ? d : 1.f - d;

    bool allpos = true, allnp = true, anyz = false;
    #pragma unroll
    for (int m = 0; m < 9; ++m) {
        allpos = allpos && (f[m] > 0.f);
        allnp  = allnp  && (f[m] <= 0.f);
        anyz   = anyz   || (f[m] == 0.f);
    }
    if (allpos) d = 1.f;
    if (allnp)  d = 0.f;
    if (anyz)   d = (d > 0.f) ? 1.f : 0.f;

    return fminf(fmaxf(d, 0.f), 1.f);
}

// ---------------------------------------------------------------------------
// Kernel 2: one thread per output pixel (r,p), t = r*256 + p.
//   f[q*3+s] = W[3r+s][3p+q]
//   out = area * ideal_wavel / 2     (pi cancels)
// W is 2.36 MB, L2-resident right after kernel 1.
// ---------------------------------------------------------------------------
__global__ __launch_bounds__(256) void climb_kernel(
    const float* __restrict__ W,
    const float* __restrict__ wavel,
    float* __restrict__ out)
{
    const int t = blockIdx.x * 256 + threadIdx.x;   // 0 .. 65535
    const int r = t >> 8;
    const int p = t & 255;

    const float* __restrict__ base = W + (3 * r) * NPIX + 3 * p;
    float f[9];
    #pragma unroll
    for (int s = 0; s < 3; ++s)
        #pragma unroll
        for (int q = 0; q < 3; ++q)
            f[q * 3 + s] = base[s * NPIX + q];

    out[t] = climb_area(f) * 0.5f * wavel[0];
}

// ---------------------------------------------------------------------------
// Fallback: fully fused (used only if d_ws can't hold W). Same math,
// basis read directly with 9 scalar loads per term (aggregate-coalesced).
// ---------------------------------------------------------------------------
__global__ __launch_bounds__(256) void fused_kernel(
    const float* __restrict__ basis,
    const float* __restrict__ coeffs,
    const float* __restrict__ wavel,
    float* __restrict__ out)
{
    __shared__ float sc[NTERMS];
    if (threadIdx.x < NTERMS) sc[threadIdx.x] = coeffs[threadIdx.x];
    __syncthreads();

    const int t = blockIdx.x * 256 + threadIdx.x;
    const int r = t >> 8;
    const int p = t & 255;

    const float* __restrict__ base = basis + (3 * r) * NPIX + 3 * p;
    float f[9];
    #pragma unroll
    for (int m = 0; m < 9; ++m) f[m] = 0.f;

    for (int n = 0; n < NTERMS; ++n) {
        const float* __restrict__ bn = base + (long)n * NPIX * NPIX;
        float cn = sc[n];
        #pragma unroll
        for (int s = 0; s < 3; ++s)
            #pragma unroll
            for (int q = 0; q < 3; ++q)
                f[q * 3 + s] = fmaf(bn[s * NPIX + q], cn, f[q * 3 + s]);
    }

    out[t] = climb_area(f) * 0.5f * wavel[0];
}

extern "C" void kernel_launch(void* const* d_in, const int* in_sizes, int n_in,
                              void* d_out, int out_size, void* d_ws, size_t ws_size,
                              hipStream_t stream)
{
    const float* basis  = (const float*)d_in[0];  // 128*768*768 f32
    const float* coeffs = (const float*)d_in[1];  // 128 f32
    const float* wavel  = (const float*)d_in[2];  // 1 f32
    float* out = (float*)d_out;                   // 256*256 f32

    const size_t w_bytes = (size_t)NPIX * NPIX * sizeof(float);  // 2.36 MB
    if (ws_size >= w_bytes) {
        float* W = (float*)d_ws;
        latent_kernel<<<(NPIX * (NPIX / 4)) / 256, 256, 0, stream>>>(basis, coeffs, W);
        climb_kernel<<<(PP * PP) / 256, 256, 0, stream>>>(W, wavel, out);
    } else {
        fused_kernel<<<(PP * PP) / 256, 256, 0, stream>>>(basis, coeffs, wavel, out);
    }
}

// Round 4
// 373.282 us; speedup vs baseline: 1.0666x; 1.0666x over previous
//
#include <hip/hip_runtime.h>

#define NPIX   768
#define PP     256
#define NTERMS 128
#define EPSF   1e-15f

// Native Clang vector type: __builtin_nontemporal_load requires a true
// vector type (HIP's float4 is a class and is rejected).
typedef float f32x4 __attribute__((ext_vector_type(4)));

// ---------------------------------------------------------------------------
// Kernel 1: W[i][j] = sum_n basis[n][i][j] * coeffs[n]
// 2304 blocks x 64 threads = exactly 9 waves/CU on 256 CUs (balanced).
// One thread per float4 of W. 16-deep explicit load batching (16 outstanding
// global_load_dwordx4 per lane) + non-temporal loads (stream-once data).
// Memory-bound: 302 MB streamed once; floor ~48 us at 6.3 TB/s.
// ---------------------------------------------------------------------------
__global__ __launch_bounds__(64) void latent_kernel(
    const float* __restrict__ basis,
    const float* __restrict__ coeffs,
    float* __restrict__ W)
{
    __shared__ float sc[NTERMS];
    sc[threadIdx.x]      = coeffs[threadIdx.x];
    sc[threadIdx.x + 64] = coeffs[threadIdx.x + 64];
    __syncthreads();

    const int t = blockIdx.x * 64 + threadIdx.x;       // 0 .. 147455
    const f32x4* __restrict__ b4 = (const f32x4*)basis;
    const long stride = NPIX * (NPIX / 4);             // 147456 f32x4 per term
    const f32x4* __restrict__ p = b4 + t;

    f32x4 acc = {0.f, 0.f, 0.f, 0.f};

    #pragma unroll
    for (int nb = 0; nb < NTERMS; nb += 16) {
        f32x4 v[16];
        #pragma unroll
        for (int k = 0; k < 16; ++k)
            v[k] = __builtin_nontemporal_load(p + (long)(nb + k) * stride);
        #pragma unroll
        for (int k = 0; k < 16; ++k) {
            const float cn = sc[nb + k];
            acc.x = fmaf(v[k].x, cn, acc.x);
            acc.y = fmaf(v[k].y, cn, acc.y);
            acc.z = fmaf(v[k].z, cn, acc.z);
            acc.w = fmaf(v[k].w, cn, acc.w);
        }
    }
    ((f32x4*)W)[t] = acc;
}

// ---------------------------------------------------------------------------
// Closed-form CLIMB area for one 3x3 patch.
// f[m], m = q*3+s  corresponds to sample at x = s/2, y = q/2.
// Least-squares plane fit (regressors orthogonal after centering):
//   a = (sum_{s=2} - sum_{s=0}) / 3
//   b = (sum_{q=2} - sum_{q=0}) / 3
//   c = mean - 0.5*(a+b)
// ---------------------------------------------------------------------------
__device__ __forceinline__ float climb_area(const float f[9])
{
    float sum = 0.f;
    #pragma unroll
    for (int m = 0; m < 9; ++m) sum += f[m];
    float mean = sum * (1.f / 9.f);

    float a = (f[2] + f[5] + f[8] - f[0] - f[3] - f[6]) * (1.f / 3.f);
    float b = (f[6] + f[7] + f[8] - f[0] - f[1] - f[2]) * (1.f / 3.f);
    float c = mean - 0.5f * (a + b);

    if (a == 0.f) a = EPSF;
    if (b == 0.f) b = EPSF;
    if (c == 0.f) c = EPSF;

    float x1 = (-b - c) / a;
    float x2 = -c / a;
    float lo = fminf(x1, x2);
    float hi = fmaxf(x1, x2);
    x1 = fmaxf(lo, 0.f);
    x2 = fminf(hi, 1.f);

    float cb = -c / b;
    float ab = 0.5f * (a / b);
    float d = x1 + cb * x2 - ab * x2 * x2 - cb * x1 + ab * x1 * x1;

    d = (d >= 0.5f) ? d : 1.f - d;
    d = (mean >= 0.f) ? d : 1.f - d;

    bool allpos = true, allnp = true, anyz = false;
    #pragma unroll
    for (int m = 0; m < 9; ++m) {
        allpos = allpos && (f[m] > 0.f);
        allnp  = allnp  && (f[m] <= 0.f);
        anyz   = anyz   || (f[m] == 0.f);
    }
    if (allpos) d = 1.f;
    if (allnp)  d = 0.f;
    if (anyz)   d = (d > 0.f) ? 1.f : 0.f;

    return fminf(fmaxf(d, 0.f), 1.f);
}

// ---------------------------------------------------------------------------
// Kernel 2: one thread per output pixel (r,p), t = r*256 + p.
//   f[q*3+s] = W[3r+s][3p+q]
//   out = area * ideal_wavel / 2     (pi cancels)
// W is 2.36 MB, L2-resident right after kernel 1.
// ---------------------------------------------------------------------------
__global__ __launch_bounds__(256) void climb_kernel(
    const float* __restrict__ W,
    const float* __restrict__ wavel,
    float* __restrict__ out)
{
    const int t = blockIdx.x * 256 + threadIdx.x;   // 0 .. 65535
    const int r = t >> 8;
    const int p = t & 255;

    const float* __restrict__ base = W + (3 * r) * NPIX + 3 * p;
    float f[9];
    #pragma unroll
    for (int s = 0; s < 3; ++s)
        #pragma unroll
        for (int q = 0; q < 3; ++q)
            f[q * 3 + s] = base[s * NPIX + q];

    out[t] = climb_area(f) * 0.5f * wavel[0];
}

// ---------------------------------------------------------------------------
// Fallback: fully fused (used only if d_ws can't hold W). Same math,
// basis read directly with 9 scalar loads per term (aggregate-coalesced).
// ---------------------------------------------------------------------------
__global__ __launch_bounds__(256) void fused_kernel(
    const float* __restrict__ basis,
    const float* __restrict__ coeffs,
    const float* __restrict__ wavel,
    float* __restrict__ out)
{
    __shared__ float sc[NTERMS];
    if (threadIdx.x < NTERMS) sc[threadIdx.x] = coeffs[threadIdx.x];
    __syncthreads();

    const int t = blockIdx.x * 256 + threadIdx.x;
    const int r = t >> 8;
    const int p = t & 255;

    const float* __restrict__ base = basis + (3 * r) * NPIX + 3 * p;
    float f[9];
    #pragma unroll
    for (int m = 0; m < 9; ++m) f[m] = 0.f;

    for (int n = 0; n < NTERMS; ++n) {
        const float* __restrict__ bn = base + (long)n * NPIX * NPIX;
        float cn = sc[n];
        #pragma unroll
        for (int s = 0; s < 3; ++s)
            #pragma unroll
            for (int q = 0; q < 3; ++q)
                f[q * 3 + s] = fmaf(bn[s * NPIX + q], cn, f[q * 3 + s]);
    }

    out[t] = climb_area(f) * 0.5f * wavel[0];
}

extern "C" void kernel_launch(void* const* d_in, const int* in_sizes, int n_in,
                              void* d_out, int out_size, void* d_ws, size_t ws_size,
                              hipStream_t stream)
{
    const float* basis  = (const float*)d_in[0];  // 128*768*768 f32
    const float* coeffs = (const float*)d_in[1];  // 128 f32
    const float* wavel  = (const float*)d_in[2];  // 1 f32
    float* out = (float*)d_out;                   // 256*256 f32

    const size_t w_bytes = (size_t)NPIX * NPIX * sizeof(float);  // 2.36 MB
    if (ws_size >= w_bytes) {
        float* W = (float*)d_ws;
        latent_kernel<<<NPIX * (NPIX / 4) / 64, 64, 0, stream>>>(basis, coeffs, W);
        climb_kernel<<<(PP * PP) / 256, 256, 0, stream>>>(W, wavel, out);
    } else {
        fused_kernel<<<(PP * PP) / 256, 256, 0, stream>>>(basis, coeffs, wavel, out);
    }
}

// Round 5
// 372.464 us; speedup vs baseline: 1.0689x; 1.0022x over previous
//
#include <hip/hip_runtime.h>

#define NPIX   768
#define PP     256
#define NTERMS 128
#define EPSF   1e-15f

// Native Clang vector type: __builtin_nontemporal_load requires a true
// vector type (HIP's float4 is a class and is rejected).
typedef float f32x4 __attribute__((ext_vector_type(4)));

#define NV4   (NPIX * NPIX / 4)   // 147456 f32x4 per 768x768 plane
#define KCH   2                   // split-K chunks
#define KPER  (NTERMS / KCH)      // 64 terms per chunk

// ---------------------------------------------------------------------------
// Kernel 1 (split-K): Wpart[c][t] = sum_{n in chunk c} basis[n][t] * coeffs[n]
// Grid (2304, 2) x 64 threads = 4608 blocks = 18 waves/CU (4.5/SIMD),
// perfectly balanced across 256 CUs. One thread per f32x4 of one chunk.
// Outer loop unroll 1: exactly one 16-deep non-temporal load batch in
// flight (~80 VGPR, no spill), 256 B/lane outstanding.
// Memory-bound: 302 MB streamed once; floor ~48 us at 6.3 TB/s.
// ---------------------------------------------------------------------------
__global__ __launch_bounds__(64) void latent_kernel(
    const float* __restrict__ basis,
    const float* __restrict__ coeffs,
    float* __restrict__ Wpart)          // KCH * NV4 f32x4
{
    __shared__ float sc[KPER];
    const int c  = blockIdx.y;          // K-chunk 0..KCH-1
    const int n0 = c * KPER;
    sc[threadIdx.x] = coeffs[n0 + threadIdx.x];
    __syncthreads();

    const int t = blockIdx.x * 64 + threadIdx.x;       // 0 .. NV4-1
    const long stride = NV4;                           // f32x4 per plane
    const f32x4* __restrict__ p = (const f32x4*)basis + (long)n0 * stride + t;

    f32x4 acc = {0.f, 0.f, 0.f, 0.f};

    #pragma unroll 1
    for (int nb = 0; nb < KPER; nb += 16) {
        f32x4 v[16];
        #pragma unroll
        for (int k = 0; k < 16; ++k)
            v[k] = __builtin_nontemporal_load(p + (long)(nb + k) * stride);
        #pragma unroll
        for (int k = 0; k < 16; ++k) {
            const float cn = sc[nb + k];
            acc.x = fmaf(v[k].x, cn, acc.x);
            acc.y = fmaf(v[k].y, cn, acc.y);
            acc.z = fmaf(v[k].z, cn, acc.z);
            acc.w = fmaf(v[k].w, cn, acc.w);
        }
    }
    ((f32x4*)Wpart)[(long)c * NV4 + t] = acc;
}

// ---------------------------------------------------------------------------
// Closed-form CLIMB area for one 3x3 patch.
// f[m], m = q*3+s  corresponds to sample at x = s/2, y = q/2.
// Least-squares plane fit (regressors orthogonal after centering):
//   a = (sum_{s=2} - sum_{s=0}) / 3
//   b = (sum_{q=2} - sum_{q=0}) / 3
//   c = mean - 0.5*(a+b)
// ---------------------------------------------------------------------------
__device__ __forceinline__ float climb_area(const float f[9])
{
    float sum = 0.f;
    #pragma unroll
    for (int m = 0; m < 9; ++m) sum += f[m];
    float mean = sum * (1.f / 9.f);

    float a = (f[2] + f[5] + f[8] - f[0] - f[3] - f[6]) * (1.f / 3.f);
    float b = (f[6] + f[7] + f[8] - f[0] - f[1] - f[2]) * (1.f / 3.f);
    float c = mean - 0.5f * (a + b);

    if (a == 0.f) a = EPSF;
    if (b == 0.f) b = EPSF;
    if (c == 0.f) c = EPSF;

    float x1 = (-b - c) / a;
    float x2 = -c / a;
    float lo = fminf(x1, x2);
    float hi = fmaxf(x1, x2);
    x1 = fmaxf(lo, 0.f);
    x2 = fminf(hi, 1.f);

    float cb = -c / b;
    float ab = 0.5f * (a / b);
    float d = x1 + cb * x2 - ab * x2 * x2 - cb * x1 + ab * x1 * x1;

    d = (d >= 0.5f) ? d : 1.f - d;
    d = (mean >= 0.f) ? d : 1.f - d;

    bool allpos = true, allnp = true, anyz = false;
    #pragma unroll
    for (int m = 0; m < 9; ++m) {
        allpos = allpos && (f[m] > 0.f);
        allnp  = allnp  && (f[m] <= 0.f);
        anyz   = anyz   || (f[m] == 0.f);
    }
    if (allpos) d = 1.f;
    if (allnp)  d = 0.f;
    if (anyz)   d = (d > 0.f) ? 1.f : 0.f;

    return fminf(fmaxf(d, 0.f), 1.f);
}

// ---------------------------------------------------------------------------
// Kernel 2: one thread per output pixel (r,p), t = r*256 + p.
//   f[q*3+s] = sum_c Wpart[c][3r+s][3p+q]   (split-K reduction folded in)
//   out = area * ideal_wavel / 2            (pi cancels)
// Wpart is 2*2.36 MB, L2-hot right after kernel 1.
// ---------------------------------------------------------------------------
__global__ __launch_bounds__(256) void climb_kernel(
    const float* __restrict__ Wpart,
    const float* __restrict__ wavel,
    float* __restrict__ out)
{
    const int t = blockIdx.x * 256 + threadIdx.x;   // 0 .. 65535
    const int r = t >> 8;
    const int p = t & 255;

    const float* __restrict__ b0 = Wpart + (3 * r) * NPIX + 3 * p;
    const float* __restrict__ b1 = b0 + (long)NV4 * 4;   // chunk 1 plane
    float f[9];
    #pragma unroll
    for (int s = 0; s < 3; ++s)
        #pragma unroll
        for (int q = 0; q < 3; ++q)
            f[q * 3 + s] = b0[s * NPIX + q] + b1[s * NPIX + q];

    out[t] = climb_area(f) * 0.5f * wavel[0];
}

// ---------------------------------------------------------------------------
// Fallback: fully fused (used only if d_ws can't hold Wpart). Same math,
// basis read directly with 9 scalar loads per term (aggregate-coalesced).
// ---------------------------------------------------------------------------
__global__ __launch_bounds__(256) void fused_kernel(
    const float* __restrict__ basis,
    const float* __restrict__ coeffs,
    const float* __restrict__ wavel,
    float* __restrict__ out)
{
    __shared__ float sc[NTERMS];
    if (threadIdx.x < NTERMS) sc[threadIdx.x] = coeffs[threadIdx.x];
    __syncthreads();

    const int t = blockIdx.x * 256 + threadIdx.x;
    const int r = t >> 8;
    const int p = t & 255;

    const float* __restrict__ base = basis + (3 * r) * NPIX + 3 * p;
    float f[9];
    #pragma unroll
    for (int m = 0; m < 9; ++m) f[m] = 0.f;

    for (int n = 0; n < NTERMS; ++n) {
        const float* __restrict__ bn = base + (long)n * NPIX * NPIX;
        float cn = sc[n];
        #pragma unroll
        for (int s = 0; s < 3; ++s)
            #pragma unroll
            for (int q = 0; q < 3; ++q)
                f[q * 3 + s] = fmaf(bn[s * NPIX + q], cn, f[q * 3 + s]);
    }

    out[t] = climb_area(f) * 0.5f * wavel[0];
}

extern "C" void kernel_launch(void* const* d_in, const int* in_sizes, int n_in,
                              void* d_out, int out_size, void* d_ws, size_t ws_size,
                              hipStream_t stream)
{
    const float* basis  = (const float*)d_in[0];  // 128*768*768 f32
    const float* coeffs = (const float*)d_in[1];  // 128 f32
    const float* wavel  = (const float*)d_in[2];  // 1 f32
    float* out = (float*)d_out;                   // 256*256 f32

    const size_t w_bytes = (size_t)KCH * NPIX * NPIX * sizeof(float);  // 4.7 MB
    if (ws_size >= w_bytes) {
        float* W = (float*)d_ws;
        dim3 grid(NV4 / 64, KCH, 1);
        latent_kernel<<<grid, 64, 0, stream>>>(basis, coeffs, W);
        climb_kernel<<<(PP * PP) / 256, 256, 0, stream>>>(W, wavel, out);
    } else {
        fused_kernel<<<(PP * PP) / 256, 256, 0, stream>>>(basis, coeffs, wavel, out);
    }
}

// Round 6
// 371.937 us; speedup vs baseline: 1.0704x; 1.0014x over previous
//
#include <hip/hip_runtime.h>

#define NPIX   768
#define PP     256
#define NTERMS 128
#define EPSF   1e-15f

// Native Clang vector type: __builtin_nontemporal_load requires a true
// vector type (HIP's float4 is a class and is rejected).
typedef float f32x4 __attribute__((ext_vector_type(4)));

#define NV4   (NPIX * NPIX / 4)   // 147456 f32x4 per 768x768 plane

// ---------------------------------------------------------------------------
// Kernel 1: W[t] = sum_n basis[n][t] * coeffs[n]
// DRAM-locality shape: 768 blocks x 64 thr = exactly 3 blocks/CU (perfect
// balance). Each block owns 192 consecutive f32x4 (3 KB) of W; per plane one
// wave reads its 3 KB contiguously (3 loads/lane at +0/+1KB/+2KB immediate
// offsets), planes in PAIRS -> only 2 concurrent 3KB streams per block
// (vs 16x 1KB before) to restore DRAM row-buffer locality.
// 6 outstanding 16B loads/lane = 18 KB in flight/CU (2x the ~9 KB needed).
// ---------------------------------------------------------------------------
__global__ __launch_bounds__(64) void latent_kernel(
    const float* __restrict__ basis,
    const float* __restrict__ coeffs,
    float* __restrict__ W)
{
    __shared__ float sc[NTERMS];
    sc[threadIdx.x]      = coeffs[threadIdx.x];
    sc[threadIdx.x + 64] = coeffs[threadIdx.x + 64];
    __syncthreads();

    const int t0 = blockIdx.x * 192 + threadIdx.x;     // first of 3 f32x4
    const f32x4* __restrict__ b4 = (const f32x4*)basis;

    f32x4 a0 = {0.f, 0.f, 0.f, 0.f};
    f32x4 a1 = {0.f, 0.f, 0.f, 0.f};
    f32x4 a2 = {0.f, 0.f, 0.f, 0.f};

    #pragma unroll 1
    for (int n = 0; n < NTERMS; n += 2) {
        const f32x4* __restrict__ pa = b4 + (long)n * NV4 + t0;
        const f32x4* __restrict__ pb = pa + NV4;
        // plane n: one 3 KB contiguous chunk (offsets are immediates)
        f32x4 v0 = __builtin_nontemporal_load(pa);
        f32x4 v1 = __builtin_nontemporal_load(pa + 64);
        f32x4 v2 = __builtin_nontemporal_load(pa + 128);
        // plane n+1: second stream
        f32x4 v3 = __builtin_nontemporal_load(pb);
        f32x4 v4 = __builtin_nontemporal_load(pb + 64);
        f32x4 v5 = __builtin_nontemporal_load(pb + 128);

        const float ca = sc[n];
        const float cb = sc[n + 1];
        a0.x = fmaf(v0.x, ca, a0.x); a0.y = fmaf(v0.y, ca, a0.y);
        a0.z = fmaf(v0.z, ca, a0.z); a0.w = fmaf(v0.w, ca, a0.w);
        a1.x = fmaf(v1.x, ca, a1.x); a1.y = fmaf(v1.y, ca, a1.y);
        a1.z = fmaf(v1.z, ca, a1.z); a1.w = fmaf(v1.w, ca, a1.w);
        a2.x = fmaf(v2.x, ca, a2.x); a2.y = fmaf(v2.y, ca, a2.y);
        a2.z = fmaf(v2.z, ca, a2.z); a2.w = fmaf(v2.w, ca, a2.w);
        a0.x = fmaf(v3.x, cb, a0.x); a0.y = fmaf(v3.y, cb, a0.y);
        a0.z = fmaf(v3.z, cb, a0.z); a0.w = fmaf(v3.w, cb, a0.w);
        a1.x = fmaf(v4.x, cb, a1.x); a1.y = fmaf(v4.y, cb, a1.y);
        a1.z = fmaf(v4.z, cb, a1.z); a1.w = fmaf(v4.w, cb, a1.w);
        a2.x = fmaf(v5.x, cb, a2.x); a2.y = fmaf(v5.y, cb, a2.y);
        a2.z = fmaf(v5.z, cb, a2.z); a2.w = fmaf(v5.w, cb, a2.w);
    }

    f32x4* __restrict__ W4 = (f32x4*)W;
    W4[t0]       = a0;
    W4[t0 + 64]  = a1;
    W4[t0 + 128] = a2;
}

// ---------------------------------------------------------------------------
// Closed-form CLIMB area for one 3x3 patch.
// f[m], m = q*3+s  corresponds to sample at x = s/2, y = q/2.
// Least-squares plane fit (regressors orthogonal after centering):
//   a = (sum_{s=2} - sum_{s=0}) / 3
//   b = (sum_{q=2} - sum_{q=0}) / 3
//   c = mean - 0.5*(a+b)
// ---------------------------------------------------------------------------
__device__ __forceinline__ float climb_area(const float f[9])
{
    float sum = 0.f;
    #pragma unroll
    for (int m = 0; m < 9; ++m) sum += f[m];
    float mean = sum * (1.f / 9.f);

    float a = (f[2] + f[5] + f[8] - f[0] - f[3] - f[6]) * (1.f / 3.f);
    float b = (f[6] + f[7] + f[8] - f[0] - f[1] - f[2]) * (1.f / 3.f);
    float c = mean - 0.5f * (a + b);

    if (a == 0.f) a = EPSF;
    if (b == 0.f) b = EPSF;
    if (c == 0.f) c = EPSF;

    float x1 = (-b - c) / a;
    float x2 = -c / a;
    float lo = fminf(x1, x2);
    float hi = fmaxf(x1, x2);
    x1 = fmaxf(lo, 0.f);
    x2 = fminf(hi, 1.f);

    float cb = -c / b;
    float ab = 0.5f * (a / b);
    float d = x1 + cb * x2 - ab * x2 * x2 - cb * x1 + ab * x1 * x1;

    d = (d >= 0.5f) ? d : 1.f - d;
    d = (mean >= 0.f) ? d : 1.f - d;

    bool allpos = true, allnp = true, anyz = false;
    #pragma unroll
    for (int m = 0; m < 9; ++m) {
        allpos = allpos && (f[m] > 0.f);
        allnp  = allnp  && (f[m] <= 0.f);
        anyz   = anyz   || (f[m] == 0.f);
    }
    if (allpos) d = 1.f;
    if (allnp)  d = 0.f;
    if (anyz)   d = (d > 0.f) ? 1.f : 0.f;

    return fminf(fmaxf(d, 0.f), 1.f);
}

// ---------------------------------------------------------------------------
// Kernel 2: one thread per output pixel (r,p), t = r*256 + p.
//   f[q*3+s] = W[3r+s][3p+q]
//   out = area * ideal_wavel / 2     (pi cancels)
// W is 2.36 MB, L2-resident right after kernel 1.
// ---------------------------------------------------------------------------
__global__ __launch_bounds__(256) void climb_kernel(
    const float* __restrict__ W,
    const float* __restrict__ wavel,
    float* __restrict__ out)
{
    const int t = blockIdx.x * 256 + threadIdx.x;   // 0 .. 65535
    const int r = t >> 8;
    const int p = t & 255;

    const float* __restrict__ base = W + (3 * r) * NPIX + 3 * p;
    float f[9];
    #pragma unroll
    for (int s = 0; s < 3; ++s)
        #pragma unroll
        for (int q = 0; q < 3; ++q)
            f[q * 3 + s] = base[s * NPIX + q];

    out[t] = climb_area(f) * 0.5f * wavel[0];
}

// ---------------------------------------------------------------------------
// Fallback: fully fused (used only if d_ws can't hold W). Same math,
// basis read directly with 9 scalar loads per term (aggregate-coalesced).
// ---------------------------------------------------------------------------
__global__ __launch_bounds__(256) void fused_kernel(
    const float* __restrict__ basis,
    const float* __restrict__ coeffs,
    const float* __restrict__ wavel,
    float* __restrict__ out)
{
    __shared__ float sc[NTERMS];
    if (threadIdx.x < NTERMS) sc[threadIdx.x] = coeffs[threadIdx.x];
    __syncthreads();

    const int t = blockIdx.x * 256 + threadIdx.x;
    const int r = t >> 8;
    const int p = t & 255;

    const float* __restrict__ base = basis + (3 * r) * NPIX + 3 * p;
    float f[9];
    #pragma unroll
    for (int m = 0; m < 9; ++m) f[m] = 0.f;

    for (int n = 0; n < NTERMS; ++n) {
        const float* __restrict__ bn = base + (long)n * NPIX * NPIX;
        float cn = sc[n];
        #pragma unroll
        for (int s = 0; s < 3; ++s)
            #pragma unroll
            for (int q = 0; q < 3; ++q)
                f[q * 3 + s] = fmaf(bn[s * NPIX + q], cn, f[q * 3 + s]);
    }

    out[t] = climb_area(f) * 0.5f * wavel[0];
}

extern "C" void kernel_launch(void* const* d_in, const int* in_sizes, int n_in,
                              void* d_out, int out_size, void* d_ws, size_t ws_size,
                              hipStream_t stream)
{
    const float* basis  = (const float*)d_in[0];  // 128*768*768 f32
    const float* coeffs = (const float*)d_in[1];  // 128 f32
    const float* wavel  = (const float*)d_in[2];  // 1 f32
    float* out = (float*)d_out;                   // 256*256 f32

    const size_t w_bytes = (size_t)NPIX * NPIX * sizeof(float);  // 2.36 MB
    if (ws_size >= w_bytes) {
        float* W = (float*)d_ws;
        latent_kernel<<<NV4 / 192, 64, 0, stream>>>(basis, coeffs, W);
        climb_kernel<<<(PP * PP) / 256, 256, 0, stream>>>(W, wavel, out);
    } else {
        fused_kernel<<<(PP * PP) / 256, 256, 0, stream>>>(basis, coeffs, wavel, out);
    }
}